// Round 1
// baseline (848.617 us; speedup 1.0000x reference)
//
#include <hip/hip_runtime.h>
#include <math.h>

#define NN   4096
#define KK   20
#define CAP  28
#define BLK  128                 // 2 waves
#define PPB  128                 // points per block
#define BPB  (NN / PPB)          // 32 blocks per batch

__device__ __forceinline__ float dist2(float ax, float ay, float az,
                                       float bx, float by, float bz) {
  float dx = ax - bx, dy = ay - by, dz = az - bz;
  return fmaf(dx, dx, fmaf(dy, dy, dz * dz));
}

__global__ __launch_bounds__(BLK, 1)
void edgeconv_kernel(const float* __restrict__ x,
                     const float* __restrict__ W,
                     const float* __restrict__ bias,
                     float* __restrict__ out) {
  __shared__ float xs[NN + 8], ys[NN + 8], zs[NN + 8];
  __shared__ int idxbuf[PPB][CAP];

  const int tid  = threadIdx.x;
  const int bb   = blockIdx.x / BPB;
  const int blk  = blockIdx.x % BPB;
  const int base = bb * NN;

  // stage batch points into LDS (SoA)
  for (int p = tid; p < NN; p += BLK) {
    xs[p] = x[(size_t)(base + p) * 3 + 0];
    ys[p] = x[(size_t)(base + p) * 3 + 1];
    zs[p] = x[(size_t)(base + p) * 3 + 2];
  }
  if (tid < 8) { xs[NN + tid] = 0.f; ys[NN + tid] = 0.f; zs[NN + tid] = 0.f; }
  __syncthreads();

  const int myp = blk * PPB + tid;            // point id within batch
  const float mx = xs[myp], my = ys[myp], mz = zs[myp];

  // ---------------- Phase A: exact 20 smallest distance VALUES ----------------
  float nd[KK];                                // descending: nd[0] = current max
  #pragma unroll
  for (int t = 0; t < KK; ++t) nd[t] = INFINITY;

  for (int j = 0; j < NN; j += 2) {
    const float d0 = dist2(mx, my, mz, xs[j],     ys[j],     zs[j]);
    const float d1 = dist2(mx, my, mz, xs[j + 1], ys[j + 1], zs[j + 1]);
    if (d0 < nd[0] && j != myp) {
      #pragma unroll
      for (int t = 0; t < KK - 1; ++t)
        nd[t] = fmaxf(nd[t + 1], fminf(nd[t], d0));
      nd[KK - 1] = fminf(nd[KK - 1], d0);
    }
    if (d1 < nd[0] && (j + 1) != myp) {
      #pragma unroll
      for (int t = 0; t < KK - 1; ++t)
        nd[t] = fmaxf(nd[t + 1], fminf(nd[t], d1));
      nd[KK - 1] = fminf(nd[KK - 1], d1);
    }
  }
  const float tau = nd[0];                     // exact K-th smallest distance

  // ---------------- Phase B: collect indices with d <= tau -------------------
  int cnt = 0;
  for (int j = 0; j < NN; ++j) {
    const float d = dist2(mx, my, mz, xs[j], ys[j], zs[j]);
    if (d <= tau && j != myp) {
      if (cnt < CAP) idxbuf[tid][cnt] = j;
      ++cnt;
    }
  }

  // ---------------- Phase C: tie fix-up (rare; matches top_k tie-break) ------
  if (cnt > KK) {
    const int m = cnt < CAP ? cnt : CAP;
    int nless = 0;
    for (int e = 0; e < m; ++e) {
      const int j = idxbuf[tid][e];
      const float d = dist2(mx, my, mz, xs[j], ys[j], zs[j]);
      nless += (d < tau) ? 1 : 0;
    }
    int w = 0, eqk = 0;
    for (int e = 0; e < m; ++e) {
      const int j = idxbuf[tid][e];
      const float d = dist2(mx, my, mz, xs[j], ys[j], zs[j]);
      const bool is_eq = !(d < tau);
      const bool keep = !is_eq || (eqk < KK - nless);
      if (keep) {
        idxbuf[tid][w] = j;
        ++w;
        if (is_eq) ++eqk;
      }
      if (w >= KK) break;
    }
  }
  __syncthreads();

  // ---------------- Feature phase: lane = output channel ---------------------
  const int lane = tid & 63;
  const int wv   = tid >> 6;
  const float w0 = W[0 * 64 + lane], w1 = W[1 * 64 + lane], w2 = W[2 * 64 + lane];
  const float w3 = W[3 * 64 + lane], w4 = W[4 * 64 + lane], w5 = W[5 * 64 + lane];
  const float bo = bias[lane];

  for (int p = 0; p < 64; ++p) {
    const int prow = wv * 64 + p;              // row within block
    const int pid  = blk * PPB + prow;         // point id within batch
    const float xi0 = xs[pid], xi1 = ys[pid], xi2 = zs[pid];
    const float basev = fmaf(xi0, w0, fmaf(xi1, w1, fmaf(xi2, w2, bo)));
    float hmax = -INFINITY;
    #pragma unroll
    for (int k = 0; k < KK; ++k) {
      const int jn = idxbuf[prow][k];
      const float e0 = xs[jn] - xi0;
      const float e1 = ys[jn] - xi1;
      const float e2 = zs[jn] - xi2;
      hmax = fmaxf(hmax, fmaf(e0, w3, fmaf(e1, w4, fmaf(e2, w5, basev))));
    }
    out[(size_t)(base + pid) * 64 + lane] = fmaxf(hmax, 0.0f);
  }
}

extern "C" void kernel_launch(void* const* d_in, const int* in_sizes, int n_in,
                              void* d_out, int out_size, void* d_ws, size_t ws_size,
                              hipStream_t stream) {
  const float* x  = (const float*)d_in[0];
  // d_in[1] = batch (implicit: i / N) — unused
  const float* W  = (const float*)d_in[2];
  const float* b  = (const float*)d_in[3];
  float* out = (float*)d_out;

  dim3 grid(8 * BPB);   // 256 blocks: 8 batches x 32 blocks
  dim3 block(BLK);
  hipLaunchKernelGGL(edgeconv_kernel, grid, block, 0, stream, x, W, b, out);
}

// Round 2
// 289.104 us; speedup vs baseline: 2.9353x; 2.9353x over previous
//
#include <hip/hip_runtime.h>
#include <math.h>

#define NN    4096
#define KK    20
#define SUBS  8
#define PPB   64
#define BLK   (PPB*SUBS)        // 512 threads, 8 waves
#define TILE  512
#define NT    (NN/TILE)         // 8 tiles
#define CHUNK (TILE/SUBS)       // 64 points scanned per sub per tile
#define CAP   21                // per-sub index capacity (>=20 + tie slack)
#define BPB   (NN/PPB)          // 64 blocks per batch

#define MB_F(g,s,i) mbuf[(g)][(s)][(i)]
#define MB_I(g,s,i) (((int*)&mbuf[(g)][(s)][0])[(i)])

__device__ __forceinline__ float dist2(float ax, float ay, float az,
                                       float bx, float by, float bz) {
  float dx = ax - bx, dy = ay - by, dz = az - bz;
  return fmaf(dx, dx, fmaf(dy, dy, dz * dz));
}

__global__ __launch_bounds__(BLK, 4)
void edgeconv_kernel(const float* __restrict__ x,
                     const float* __restrict__ W,
                     const float* __restrict__ bias,
                     float* __restrict__ out) {
  __shared__ __align__(16) float tiles[2][TILE * 3];     // 12 KB, double-buffered AoS
  __shared__ __align__(16) float mbuf[PPB][SUBS][CAP];   // 42 KB: dists (A), then idx (B)
  __shared__ int cnt[PPB][SUBS];                          // 2 KB

  const int tid  = threadIdx.x;
  const int g    = tid >> 3;          // point group 0..63
  const int s    = tid & 7;           // sub-scanner 0..7
  const int bb   = blockIdx.x / BPB;
  const int blk  = blockIdx.x % BPB;
  const int base = bb * NN;
  const int myp  = blk * PPB + g;

  const float mx = x[(size_t)(base + myp) * 3 + 0];
  const float my = x[(size_t)(base + myp) * 3 + 1];
  const float mz = x[(size_t)(base + myp) * 3 + 2];

  const bool has = (tid < TILE * 3 / 4);                  // 384 staging threads
  const float4* gx0 = (const float4*)(x + (size_t)base * 3);

  float nd[KK];                                           // descending: nd[0]=max
  #pragma unroll
  for (int i = 0; i < KK; ++i) nd[i] = INFINITY;

  auto ins = [&](float d) {                               // branchless sorted insert
    #pragma unroll
    for (int t2 = 0; t2 < KK - 1; ++t2)
      nd[t2] = fmaxf(nd[t2 + 1], fminf(nd[t2], d));
    nd[KK - 1] = fminf(nd[KK - 1], d);
  };

  // ---------------- Phase A: per-sub exact top-20 values over its 512 js -----
  if (has) ((float4*)tiles[0])[tid] = gx0[tid];
  __syncthreads();
  {
    int cur = 0;
    for (int t = 0; t < NT; ++t) {
      float4 rn;
      const bool more = (t + 1 < NT);
      if (more && has) rn = gx0[(t + 1) * (TILE * 3 / 4) + tid];
      const float* tp = tiles[cur];
      const int jg0 = t * TILE + s * CHUNK;
      #pragma unroll 2
      for (int q = 0; q < CHUNK; q += 4) {
        const float4* p4 = (const float4*)(tp + (s * CHUNK + q) * 3);
        float4 v0 = p4[0], v1 = p4[1], v2 = p4[2];
        const int jg = jg0 + q;
        float d0 = dist2(mx, my, mz, v0.x, v0.y, v0.z); if (jg + 0 == myp) d0 = INFINITY;
        float d1 = dist2(mx, my, mz, v0.w, v1.x, v1.y); if (jg + 1 == myp) d1 = INFINITY;
        float d2 = dist2(mx, my, mz, v1.z, v1.w, v2.x); if (jg + 2 == myp) d2 = INFINITY;
        float d3 = dist2(mx, my, mz, v2.y, v2.z, v2.w); if (jg + 3 == myp) d3 = INFINITY;
        ins(d0); ins(d1); ins(d2); ins(d3);
      }
      if (more) {
        if (has) ((float4*)tiles[cur ^ 1])[tid] = rn;
        __syncthreads();
        cur ^= 1;
      }
    }
  }
  #pragma unroll
  for (int i = 0; i < KK; ++i) MB_F(g, s, i) = nd[KK - 1 - i];   // ascending
  __syncthreads();

  // ---------------- Merge: exact 20th-smallest of the 8x20 union -------------
  float tau;
  {
    float h0 = MB_F(g,0,0), h1 = MB_F(g,1,0), h2 = MB_F(g,2,0), h3 = MB_F(g,3,0);
    float h4 = MB_F(g,4,0), h5 = MB_F(g,5,0), h6 = MB_F(g,6,0), h7 = MB_F(g,7,0);
    int i0=0,i1=0,i2=0,i3=0,i4=0,i5=0,i6=0,i7=0;
    float mm = 0.f;
    for (int r = 0; r < KK; ++r) {
      mm = fminf(fminf(fminf(h0,h1),fminf(h2,h3)),fminf(fminf(h4,h5),fminf(h6,h7)));
      bool done = false, tk;
      tk = (h0==mm);           if (tk){++i0; h0=(i0<KK)?MB_F(g,0,i0):INFINITY;} done|=tk;
      tk = (!done && h1==mm);  if (tk){++i1; h1=(i1<KK)?MB_F(g,1,i1):INFINITY;} done|=tk;
      tk = (!done && h2==mm);  if (tk){++i2; h2=(i2<KK)?MB_F(g,2,i2):INFINITY;} done|=tk;
      tk = (!done && h3==mm);  if (tk){++i3; h3=(i3<KK)?MB_F(g,3,i3):INFINITY;} done|=tk;
      tk = (!done && h4==mm);  if (tk){++i4; h4=(i4<KK)?MB_F(g,4,i4):INFINITY;} done|=tk;
      tk = (!done && h5==mm);  if (tk){++i5; h5=(i5<KK)?MB_F(g,5,i5):INFINITY;} done|=tk;
      tk = (!done && h6==mm);  if (tk){++i6; h6=(i6<KK)?MB_F(g,6,i6):INFINITY;} done|=tk;
      tk = (!done && h7==mm);  if (tk){++i7; h7=(i7<KK)?MB_F(g,7,i7):INFINITY;} done|=tk;
    }
    tau = mm;
  }

  // ---------------- Phase B: collect indices with d <= tau -------------------
  if (has) ((float4*)tiles[0])[tid] = gx0[tid];
  __syncthreads();                       // also fences merge reads vs idx writes
  int c = 0;
  {
    int cur = 0;
    for (int t = 0; t < NT; ++t) {
      float4 rn;
      const bool more = (t + 1 < NT);
      if (more && has) rn = gx0[(t + 1) * (TILE * 3 / 4) + tid];
      const float* tp = tiles[cur];
      const int jg0 = t * TILE + s * CHUNK;
      for (int q = 0; q < CHUNK; q += 4) {
        const float4* p4 = (const float4*)(tp + (s * CHUNK + q) * 3);
        float4 v0 = p4[0], v1 = p4[1], v2 = p4[2];
        const int jg = jg0 + q;
        float d0 = dist2(mx, my, mz, v0.x, v0.y, v0.z); if (jg + 0 == myp) d0 = INFINITY;
        float d1 = dist2(mx, my, mz, v0.w, v1.x, v1.y); if (jg + 1 == myp) d1 = INFINITY;
        float d2 = dist2(mx, my, mz, v1.z, v1.w, v2.x); if (jg + 2 == myp) d2 = INFINITY;
        float d3 = dist2(mx, my, mz, v2.y, v2.z, v2.w); if (jg + 3 == myp) d3 = INFINITY;
        if (d0 <= tau) { if (c < CAP) MB_I(g, s, c) = jg + 0; ++c; }
        if (d1 <= tau) { if (c < CAP) MB_I(g, s, c) = jg + 1; ++c; }
        if (d2 <= tau) { if (c < CAP) MB_I(g, s, c) = jg + 2; ++c; }
        if (d3 <= tau) { if (c < CAP) MB_I(g, s, c) = jg + 3; ++c; }
      }
      if (more) {
        if (has) ((float4*)tiles[cur ^ 1])[tid] = rn;
        __syncthreads();
        cur ^= 1;
      }
    }
  }
  cnt[g][s] = (c < CAP) ? c : CAP;
  __syncthreads();

  // ---------------- Phase C: rare tie trim (matches top_k tie-break) ---------
  if (s == 0) {
    int m = 0;
    #pragma unroll
    for (int ss = 0; ss < SUBS; ++ss) m += cnt[g][ss];
    if (m > KK) {
      int nl = 0;
      for (int ss = 0; ss < SUBS; ++ss)
        for (int k = 0; k < cnt[g][ss]; ++k) {
          const int j = MB_I(g, ss, k);
          const float* xp = x + (size_t)(base + j) * 3;
          nl += (dist2(mx, my, mz, xp[0], xp[1], xp[2]) < tau) ? 1 : 0;
        }
      const int need = KK - nl;
      int jth = -1;
      for (int r = 0; r < need; ++r) {
        int best = 0x7fffffff;
        for (int ss = 0; ss < SUBS; ++ss)
          for (int k = 0; k < cnt[g][ss]; ++k) {
            const int j = MB_I(g, ss, k);
            const float* xp = x + (size_t)(base + j) * 3;
            const float d = dist2(mx, my, mz, xp[0], xp[1], xp[2]);
            if (!(d < tau) && j > jth && j < best) best = j;
          }
        jth = best;
      }
      for (int ss = 0; ss < SUBS; ++ss) {
        int w = 0; const int cs = cnt[g][ss];
        for (int k = 0; k < cs; ++k) {
          const int j = MB_I(g, ss, k);
          const float* xp = x + (size_t)(base + j) * 3;
          const float d = dist2(mx, my, mz, xp[0], xp[1], xp[2]);
          if ((d < tau) || (j <= jth)) { MB_I(g, ss, w) = j; ++w; }
        }
        cnt[g][ss] = w;
      }
    }
  }
  __syncthreads();

  // ---------------- Feature phase: lane = output channel ---------------------
  const int wv   = tid >> 6;           // wave 0..7
  const int lane = tid & 63;
  const float w0 = W[0*64+lane], w1 = W[1*64+lane], w2 = W[2*64+lane];
  const float w3 = W[3*64+lane], w4 = W[4*64+lane], w5 = W[5*64+lane];
  const float bo = bias[lane];

  for (int pi = 0; pi < PPB / 8; ++pi) {       // 8 points per wave
    const int p   = wv * (PPB / 8) + pi;
    const int pid = blk * PPB + p;
    const float* xi = x + (size_t)(base + pid) * 3;
    const float xi0 = xi[0], xi1 = xi[1], xi2 = xi[2];
    const float basev = fmaf(xi0, w0, fmaf(xi1, w1, fmaf(xi2, w2, bo)));
    float hmax = -INFINITY;
    for (int ss = 0; ss < SUBS; ++ss) {
      const int cs = cnt[p][ss];
      for (int k = 0; k < cs; ++k) {
        const int j = MB_I(p, ss, k);
        const float* xp = x + (size_t)(base + j) * 3;
        const float e0 = xp[0] - xi0, e1 = xp[1] - xi1, e2 = xp[2] - xi2;
        hmax = fmaxf(hmax, fmaf(e0, w3, fmaf(e1, w4, fmaf(e2, w5, basev))));
      }
    }
    out[(size_t)(base + pid) * 64 + lane] = fmaxf(hmax, 0.0f);
  }
}

extern "C" void kernel_launch(void* const* d_in, const int* in_sizes, int n_in,
                              void* d_out, int out_size, void* d_ws, size_t ws_size,
                              hipStream_t stream) {
  const float* x  = (const float*)d_in[0];
  // d_in[1] = batch (implicit: i / N) — unused
  const float* W  = (const float*)d_in[2];
  const float* b  = (const float*)d_in[3];
  float* out = (float*)d_out;

  dim3 grid(8 * BPB);   // 512 blocks: 8 batches x 64 point-groups
  dim3 block(BLK);
  hipLaunchKernelGGL(edgeconv_kernel, grid, block, 0, stream, x, W, b, out);
}

// Round 3
// 185.660 us; speedup vs baseline: 4.5708x; 1.5572x over previous
//
#include <hip/hip_runtime.h>
#include <math.h>

#define NN    4096
#define KK    20
#define SUBS  8
#define PPB   64
#define BLK   (PPB*SUBS)        // 512 threads, 8 waves
#define TILE  512
#define NT    (NN/TILE)         // 8 tiles
#define CHUNK (TILE/SUBS)       // 64 points scanned per sub per tile
#define CAP   21                // per-sub index capacity (>=20 + tie slack)
#define BPB   (NN/PPB)          // 64 blocks per batch

#define MB_F(g,s,i) mbuf[(g)][(s)][(i)]
#define MB_I(g,s,i) (((int*)&mbuf[(g)][(s)][0])[(i)])

__device__ __forceinline__ float dist2(float ax, float ay, float az,
                                       float bx, float by, float bz) {
  float dx = ax - bx, dy = ay - by, dz = az - bz;
  return fmaf(dx, dx, fmaf(dy, dy, dz * dz));
}

__global__ __launch_bounds__(BLK, 4)
void edgeconv_kernel(const float* __restrict__ x,
                     const float* __restrict__ W,
                     const float* __restrict__ bias,
                     float* __restrict__ out) {
  __shared__ __align__(16) float tiles[2][TILE * 3];     // 12 KB, double-buffered AoS
  __shared__ __align__(16) float mbuf[PPB][SUBS][CAP];   // 42 KB: dists (A), then idx (B)
  __shared__ int cnt[PPB][SUBS];                          // 2 KB

  const int tid  = threadIdx.x;
  const int g    = tid >> 3;          // point group 0..63
  const int s    = tid & 7;           // sub-scanner 0..7
  const int bb   = blockIdx.x / BPB;
  const int blk  = blockIdx.x % BPB;
  const int base = bb * NN;
  const int myp  = blk * PPB + g;

  const float mx = x[(size_t)(base + myp) * 3 + 0];
  const float my = x[(size_t)(base + myp) * 3 + 1];
  const float mz = x[(size_t)(base + myp) * 3 + 2];

  const bool has = (tid < TILE * 3 / 4);                  // 384 staging threads
  const float4* gx0 = (const float4*)(x + (size_t)base * 3);

  float nd[KK];                                           // descending: nd[0]=max
  #pragma unroll
  for (int i = 0; i < KK; ++i) nd[i] = INFINITY;

  // branchless sorted insert; with nd[t] >= nd[t+1] the step
  // max(nd[t+1], min(nd[t], d)) == median3(nd[t], nd[t+1], d)
  auto ins = [&](float d) {
    #pragma unroll
    for (int t2 = 0; t2 < KK - 1; ++t2)
      nd[t2] = __builtin_amdgcn_fmed3f(nd[t2], nd[t2 + 1], d);
    nd[KK - 1] = fminf(nd[KK - 1], d);
  };

  // ---------------- Phase A: per-sub exact top-20 values over its 512 js -----
  // Sub s starts its chunk at q0 = 4*s (wrap mod CHUNK): start bank
  // = (12*s) % 32 = {0,4,...,28} -> the 8 ds_read_b128 tile all 32 banks.
  const int q0 = (4 * s) & (CHUNK - 1);
  if (has) ((float4*)tiles[0])[tid] = gx0[tid];
  __syncthreads();
  {
    int cur = 0;
    for (int t = 0; t < NT; ++t) {
      float4 rn;
      const bool more = (t + 1 < NT);
      if (more && has) rn = gx0[(t + 1) * (TILE * 3 / 4) + tid];
      const float* tp = tiles[cur];
      const int jg0 = t * TILE + s * CHUNK;
      #pragma unroll 4
      for (int i = 0; i < CHUNK / 4; ++i) {
        const int q = (q0 + 4 * i) & (CHUNK - 1);
        const float4* p4 = (const float4*)(tp + (s * CHUNK + q) * 3);
        float4 v0 = p4[0], v1 = p4[1], v2 = p4[2];
        const int jg = jg0 + q;
        float d0 = dist2(mx, my, mz, v0.x, v0.y, v0.z); if (jg + 0 == myp) d0 = INFINITY;
        float d1 = dist2(mx, my, mz, v0.w, v1.x, v1.y); if (jg + 1 == myp) d1 = INFINITY;
        float d2 = dist2(mx, my, mz, v1.z, v1.w, v2.x); if (jg + 2 == myp) d2 = INFINITY;
        float d3 = dist2(mx, my, mz, v2.y, v2.z, v2.w); if (jg + 3 == myp) d3 = INFINITY;
        ins(d0); ins(d1); ins(d2); ins(d3);
      }
      if (more) {
        if (has) ((float4*)tiles[cur ^ 1])[tid] = rn;
        __syncthreads();
        cur ^= 1;
      }
    }
  }
  #pragma unroll
  for (int i = 0; i < KK; ++i) MB_F(g, s, i) = nd[KK - 1 - i];   // ascending
  __syncthreads();

  // ---------------- Merge: exact 20th-smallest of the 8x20 union -------------
  float tau;
  {
    float h0 = MB_F(g,0,0), h1 = MB_F(g,1,0), h2 = MB_F(g,2,0), h3 = MB_F(g,3,0);
    float h4 = MB_F(g,4,0), h5 = MB_F(g,5,0), h6 = MB_F(g,6,0), h7 = MB_F(g,7,0);
    int i0=0,i1=0,i2=0,i3=0,i4=0,i5=0,i6=0,i7=0;
    float mm = 0.f;
    for (int r = 0; r < KK; ++r) {
      mm = fminf(fminf(fminf(h0,h1),fminf(h2,h3)),fminf(fminf(h4,h5),fminf(h6,h7)));
      bool done = false, tk;
      tk = (h0==mm);           if (tk){++i0; h0=(i0<KK)?MB_F(g,0,i0):INFINITY;} done|=tk;
      tk = (!done && h1==mm);  if (tk){++i1; h1=(i1<KK)?MB_F(g,1,i1):INFINITY;} done|=tk;
      tk = (!done && h2==mm);  if (tk){++i2; h2=(i2<KK)?MB_F(g,2,i2):INFINITY;} done|=tk;
      tk = (!done && h3==mm);  if (tk){++i3; h3=(i3<KK)?MB_F(g,3,i3):INFINITY;} done|=tk;
      tk = (!done && h4==mm);  if (tk){++i4; h4=(i4<KK)?MB_F(g,4,i4):INFINITY;} done|=tk;
      tk = (!done && h5==mm);  if (tk){++i5; h5=(i5<KK)?MB_F(g,5,i5):INFINITY;} done|=tk;
      tk = (!done && h6==mm);  if (tk){++i6; h6=(i6<KK)?MB_F(g,6,i6):INFINITY;} done|=tk;
      tk = (!done && h7==mm);  if (tk){++i7; h7=(i7<KK)?MB_F(g,7,i7):INFINITY;} done|=tk;
    }
    tau = mm;
  }

  // ---------------- Phase B: collect indices with d <= tau -------------------
  if (has) ((float4*)tiles[0])[tid] = gx0[tid];
  __syncthreads();                       // also fences merge reads vs idx writes
  int c = 0;
  {
    int cur = 0;
    for (int t = 0; t < NT; ++t) {
      float4 rn;
      const bool more = (t + 1 < NT);
      if (more && has) rn = gx0[(t + 1) * (TILE * 3 / 4) + tid];
      const float* tp = tiles[cur];
      const int jg0 = t * TILE + s * CHUNK;
      for (int i = 0; i < CHUNK / 4; ++i) {
        const int q = (q0 + 4 * i) & (CHUNK - 1);
        const float4* p4 = (const float4*)(tp + (s * CHUNK + q) * 3);
        float4 v0 = p4[0], v1 = p4[1], v2 = p4[2];
        const int jg = jg0 + q;
        float d0 = dist2(mx, my, mz, v0.x, v0.y, v0.z); if (jg + 0 == myp) d0 = INFINITY;
        float d1 = dist2(mx, my, mz, v0.w, v1.x, v1.y); if (jg + 1 == myp) d1 = INFINITY;
        float d2 = dist2(mx, my, mz, v1.z, v1.w, v2.x); if (jg + 2 == myp) d2 = INFINITY;
        float d3 = dist2(mx, my, mz, v2.y, v2.z, v2.w); if (jg + 3 == myp) d3 = INFINITY;
        if (d0 <= tau) { if (c < CAP) MB_I(g, s, c) = jg + 0; ++c; }
        if (d1 <= tau) { if (c < CAP) MB_I(g, s, c) = jg + 1; ++c; }
        if (d2 <= tau) { if (c < CAP) MB_I(g, s, c) = jg + 2; ++c; }
        if (d3 <= tau) { if (c < CAP) MB_I(g, s, c) = jg + 3; ++c; }
      }
      if (more) {
        if (has) ((float4*)tiles[cur ^ 1])[tid] = rn;
        __syncthreads();
        cur ^= 1;
      }
    }
  }
  cnt[g][s] = (c < CAP) ? c : CAP;
  __syncthreads();

  // ---------------- Phase C: rare tie trim (matches top_k tie-break) ---------
  if (s == 0) {
    int m = 0;
    #pragma unroll
    for (int ss = 0; ss < SUBS; ++ss) m += cnt[g][ss];
    if (m > KK) {
      int nl = 0;
      for (int ss = 0; ss < SUBS; ++ss)
        for (int k = 0; k < cnt[g][ss]; ++k) {
          const int j = MB_I(g, ss, k);
          const float* xp = x + (size_t)(base + j) * 3;
          nl += (dist2(mx, my, mz, xp[0], xp[1], xp[2]) < tau) ? 1 : 0;
        }
      const int need = KK - nl;
      int jth = -1;
      for (int r = 0; r < need; ++r) {
        int best = 0x7fffffff;
        for (int ss = 0; ss < SUBS; ++ss)
          for (int k = 0; k < cnt[g][ss]; ++k) {
            const int j = MB_I(g, ss, k);
            const float* xp = x + (size_t)(base + j) * 3;
            const float d = dist2(mx, my, mz, xp[0], xp[1], xp[2]);
            if (!(d < tau) && j > jth && j < best) best = j;
          }
        jth = best;
      }
      for (int ss = 0; ss < SUBS; ++ss) {
        int w = 0; const int cs = cnt[g][ss];
        for (int k = 0; k < cs; ++k) {
          const int j = MB_I(g, ss, k);
          const float* xp = x + (size_t)(base + j) * 3;
          const float d = dist2(mx, my, mz, xp[0], xp[1], xp[2]);
          if ((d < tau) || (j <= jth)) { MB_I(g, ss, w) = j; ++w; }
        }
        cnt[g][ss] = w;
      }
    }
  }
  __syncthreads();

  // ---------------- Feature phase: lane = output channel ---------------------
  const int wv   = tid >> 6;           // wave 0..7
  const int lane = tid & 63;
  const float w0 = W[0*64+lane], w1 = W[1*64+lane], w2 = W[2*64+lane];
  const float w3 = W[3*64+lane], w4 = W[4*64+lane], w5 = W[5*64+lane];
  const float bo = bias[lane];

  for (int pi = 0; pi < PPB / 8; ++pi) {       // 8 points per wave
    const int p   = wv * (PPB / 8) + pi;
    const int pid = blk * PPB + p;
    const float* xi = x + (size_t)(base + pid) * 3;
    const float xi0 = xi[0], xi1 = xi[1], xi2 = xi[2];
    const float basev = fmaf(xi0, w0, fmaf(xi1, w1, fmaf(xi2, w2, bo)));
    float hmax = -INFINITY;
    for (int ss = 0; ss < SUBS; ++ss) {
      const int cs = cnt[p][ss];
      for (int k = 0; k < cs; ++k) {
        const int j = MB_I(p, ss, k);
        const float* xp = x + (size_t)(base + j) * 3;
        const float e0 = xp[0] - xi0, e1 = xp[1] - xi1, e2 = xp[2] - xi2;
        hmax = fmaxf(hmax, fmaf(e0, w3, fmaf(e1, w4, fmaf(e2, w5, basev))));
      }
    }
    out[(size_t)(base + pid) * 64 + lane] = fmaxf(hmax, 0.0f);
  }
}

extern "C" void kernel_launch(void* const* d_in, const int* in_sizes, int n_in,
                              void* d_out, int out_size, void* d_ws, size_t ws_size,
                              hipStream_t stream) {
  const float* x  = (const float*)d_in[0];
  // d_in[1] = batch (implicit: i / N) — unused
  const float* W  = (const float*)d_in[2];
  const float* b  = (const float*)d_in[3];
  float* out = (float*)d_out;

  dim3 grid(8 * BPB);   // 512 blocks: 8 batches x 64 point-groups
  dim3 block(BLK);
  hipLaunchKernelGGL(edgeconv_kernel, grid, block, 0, stream, x, W, b, out);
}

// Round 4
// 136.214 us; speedup vs baseline: 6.2300x; 1.3630x over previous
//
#include <hip/hip_runtime.h>
#include <math.h>

#define NN    4096
#define KK    20
#define SUBS  8
#define PPB   64
#define BLK   (PPB*SUBS)        // 512 threads, 8 waves
#define TILE  512
#define NT    (NN/TILE)         // 8 tiles
#define CHUNK (TILE/SUBS)       // 64 points scanned per sub per tile
#define M     6                 // per-sub short-list length (8*6=48 >= 21)
#define CAP   48                // per-point candidate capacity
#define CROW  49                // padded row stride (odd -> conflict-free)
#define BPB   (NN/PPB)          // 64 blocks per batch

__device__ __forceinline__ float dist2(float ax, float ay, float az,
                                       float bx, float by, float bz) {
  float dx = ax - bx, dy = ay - by, dz = az - bz;
  return fmaf(dx, dx, fmaf(dy, dy, dz * dz));
}

__global__ __launch_bounds__(BLK, 2)
void edgeconv_kernel(const float* __restrict__ x,
                     const float* __restrict__ W,
                     const float* __restrict__ bias,
                     float* __restrict__ out) {
  __shared__ __align__(16) float tiles[2][TILE * 3];   // 12 KB double-buffered AoS
  __shared__ float smin[PPB][CROW];                    // 12.25 KB per-sub top-6 lists
  __shared__ float dcand[PPB][CROW];                   // 12.25 KB candidate dists
  __shared__ int   jcand[PPB][CROW];                   // 12.25 KB candidate idx
  __shared__ int   pc[PPB];                            // per-point candidate count

  const int tid  = threadIdx.x;
  const int g    = tid >> 3;          // point group 0..63
  const int s    = tid & 7;           // sub-scanner 0..7
  const int bb   = blockIdx.x / BPB;
  const int blk  = blockIdx.x % BPB;
  const int base = bb * NN;
  const int myp  = blk * PPB + g;

  const float mx = x[(size_t)(base + myp) * 3 + 0];
  const float my = x[(size_t)(base + myp) * 3 + 1];
  const float mz = x[(size_t)(base + myp) * 3 + 2];

  const bool has = (tid < TILE * 3 / 4);               // 384 staging threads
  const float4* gx0 = (const float4*)(x + (size_t)base * 3);

  float nd[M];                                         // descending: nd[0]=max
  #pragma unroll
  for (int i = 0; i < M; ++i) nd[i] = INFINITY;

  // branchless sorted insert of d into descending nd[0..M-1]:
  // max(nd[t+1], min(nd[t], d)) == median3 given nd[t] >= nd[t+1]
  auto ins = [&](float d) {
    #pragma unroll
    for (int t2 = 0; t2 < M - 1; ++t2)
      nd[t2] = __builtin_amdgcn_fmed3f(nd[t2], nd[t2 + 1], d);
    nd[M - 1] = fminf(nd[M - 1], d);
  };

  // Sub s starts its chunk at q0 = 4*s (wrap): the 8 ds_read_b128 start banks
  // tile all 32 banks -> conflict-free.
  const int q0 = (4 * s) & (CHUNK - 1);

  // ---------------- Phase A: per-sub top-6 VALUES (self d=0 rides along) -----
  if (has) ((float4*)tiles[0])[tid] = gx0[tid];
  __syncthreads();
  {
    int cur = 0;
    for (int t = 0; t < NT; ++t) {
      float4 rn;
      const bool more = (t + 1 < NT);
      if (more && has) rn = gx0[(t + 1) * (TILE * 3 / 4) + tid];
      const float* tp = tiles[cur];
      #pragma unroll 4
      for (int i = 0; i < CHUNK / 4; ++i) {
        const int q = (q0 + 4 * i) & (CHUNK - 1);
        const float4* p4 = (const float4*)(tp + (s * CHUNK + q) * 3);
        float4 v0 = p4[0], v1 = p4[1], v2 = p4[2];
        const float d0 = dist2(mx, my, mz, v0.x, v0.y, v0.z);
        const float d1 = dist2(mx, my, mz, v0.w, v1.x, v1.y);
        const float d2 = dist2(mx, my, mz, v1.z, v1.w, v2.x);
        const float d3 = dist2(mx, my, mz, v2.y, v2.z, v2.w);
        ins(d0); ins(d1); ins(d2); ins(d3);
      }
      if (more) {
        if (has) ((float4*)tiles[cur ^ 1])[tid] = rn;
        __syncthreads();
        cur ^= 1;
      }
    }
  }
  #pragma unroll
  for (int i = 0; i < M; ++i) smin[g][s * M + i] = nd[M - 1 - i];  // ascending
  __syncthreads();

  // restage tile 0 + zero counters; overlaps with merge compute below
  if (has) ((float4*)tiles[0])[tid] = gx0[tid];
  if (tid < PPB) pc[tid] = 0;

  // ------- Merge: tau_hat = 21st smallest of the 48-value union (>= true tau;
  //         21st because exactly one self-zero is present in the union) -------
  float tau;
  {
    const float* L = &smin[g][0];
    float h0 = L[0*M], h1 = L[1*M], h2 = L[2*M], h3 = L[3*M];
    float h4 = L[4*M], h5 = L[5*M], h6 = L[6*M], h7 = L[7*M];
    int i0=0,i1=0,i2=0,i3=0,i4=0,i5=0,i6=0,i7=0;
    float mm = 0.f;
    for (int r = 0; r <= KK; ++r) {                    // 21 rounds
      mm = fminf(fminf(fminf(h0,h1),fminf(h2,h3)),fminf(fminf(h4,h5),fminf(h6,h7)));
      bool done = false, tk;
      tk = (h0==mm);           if (tk){++i0; h0=(i0<M)?L[0*M+i0]:INFINITY;} done|=tk;
      tk = (!done && h1==mm);  if (tk){++i1; h1=(i1<M)?L[1*M+i1]:INFINITY;} done|=tk;
      tk = (!done && h2==mm);  if (tk){++i2; h2=(i2<M)?L[2*M+i2]:INFINITY;} done|=tk;
      tk = (!done && h3==mm);  if (tk){++i3; h3=(i3<M)?L[3*M+i3]:INFINITY;} done|=tk;
      tk = (!done && h4==mm);  if (tk){++i4; h4=(i4<M)?L[4*M+i4]:INFINITY;} done|=tk;
      tk = (!done && h5==mm);  if (tk){++i5; h5=(i5<M)?L[5*M+i5]:INFINITY;} done|=tk;
      tk = (!done && h6==mm);  if (tk){++i6; h6=(i6<M)?L[6*M+i6]:INFINITY;} done|=tk;
      tk = (!done && h7==mm);  if (tk){++i7; h7=(i7<M)?L[7*M+i7]:INFINITY;} done|=tk;
    }
    tau = mm;
  }
  __syncthreads();   // tiles[0] restaged, pc zeroed, smin reads done

  // ---------------- Phase B: collect candidates d <= tau_hat -----------------
  {
    int cur = 0;
    for (int t = 0; t < NT; ++t) {
      float4 rn;
      const bool more = (t + 1 < NT);
      if (more && has) rn = gx0[(t + 1) * (TILE * 3 / 4) + tid];
      const float* tp = tiles[cur];
      const int jg0 = t * TILE + s * CHUNK;
      for (int i = 0; i < CHUNK / 4; ++i) {
        const int q = (q0 + 4 * i) & (CHUNK - 1);
        const float4* p4 = (const float4*)(tp + (s * CHUNK + q) * 3);
        float4 v0 = p4[0], v1 = p4[1], v2 = p4[2];
        const int jg = jg0 + q;
        float d0 = dist2(mx, my, mz, v0.x, v0.y, v0.z); if (jg + 0 == myp) d0 = INFINITY;
        float d1 = dist2(mx, my, mz, v0.w, v1.x, v1.y); if (jg + 1 == myp) d1 = INFINITY;
        float d2 = dist2(mx, my, mz, v1.z, v1.w, v2.x); if (jg + 2 == myp) d2 = INFINITY;
        float d3 = dist2(mx, my, mz, v2.y, v2.z, v2.w); if (jg + 3 == myp) d3 = INFINITY;
        if (d0 <= tau) { int w = atomicAdd(&pc[g], 1); if (w < CAP) { dcand[g][w] = d0; jcand[g][w] = jg + 0; } }
        if (d1 <= tau) { int w = atomicAdd(&pc[g], 1); if (w < CAP) { dcand[g][w] = d1; jcand[g][w] = jg + 1; } }
        if (d2 <= tau) { int w = atomicAdd(&pc[g], 1); if (w < CAP) { dcand[g][w] = d2; jcand[g][w] = jg + 2; } }
        if (d3 <= tau) { int w = atomicAdd(&pc[g], 1); if (w < CAP) { dcand[g][w] = d3; jcand[g][w] = jg + 3; } }
      }
      if (more) {
        if (has) ((float4*)tiles[cur ^ 1])[tid] = rn;
        __syncthreads();
        cur ^= 1;
      }
    }
  }
  __syncthreads();

  // -------- Rank phase: keep candidate iff lex-rank(d, j) < 20 (exact,
  //          order-independent; matches top_k's stable low-index tie-break) ---
  {
    const int n0 = pc[g];
    const int n = n0 < CAP ? n0 : CAP;
    int dropmask = 0, ki = 0;
    for (int k = s; k < n; k += SUBS, ++ki) {
      const float dk = dcand[g][k];
      const int   jk = jcand[g][k];
      int rank = 0;
      for (int k2 = 0; k2 < n; ++k2) {
        const float d2 = dcand[g][k2];
        const int   j2 = jcand[g][k2];
        rank += (d2 < dk || (d2 == dk && j2 < jk)) ? 1 : 0;
      }
      if (rank >= KK) dropmask |= 1 << ki;
    }
    __syncthreads();
    ki = 0;
    for (int k = s; k < n; k += SUBS, ++ki)
      if (dropmask & (1 << ki)) jcand[g][k] = -1;
  }
  __syncthreads();

  // ---------------- Feature phase: lane = output channel ---------------------
  const int wv   = tid >> 6;           // wave 0..7
  const int lane = tid & 63;
  const float w0 = W[0*64+lane], w1 = W[1*64+lane], w2 = W[2*64+lane];
  const float w3 = W[3*64+lane], w4 = W[4*64+lane], w5 = W[5*64+lane];
  const float bo = bias[lane];

  for (int pi = 0; pi < PPB / 8; ++pi) {       // 8 points per wave
    const int p   = wv * (PPB / 8) + pi;
    const int pid = blk * PPB + p;
    const float* xi = x + (size_t)(base + pid) * 3;
    const float xi0 = xi[0], xi1 = xi[1], xi2 = xi[2];
    const float basev = fmaf(xi0, w0, fmaf(xi1, w1, fmaf(xi2, w2, bo)));
    const int n0 = pc[p];
    const int n = n0 < CAP ? n0 : CAP;
    float hmax = -INFINITY;
    for (int k = 0; k < n; ++k) {              // wave-uniform loop & branch
      const int j = jcand[p][k];
      if (j >= 0) {
        const float* xp = x + (size_t)(base + j) * 3;
        const float e0 = xp[0] - xi0, e1 = xp[1] - xi1, e2 = xp[2] - xi2;
        hmax = fmaxf(hmax, fmaf(e0, w3, fmaf(e1, w4, fmaf(e2, w5, basev))));
      }
    }
    out[(size_t)(base + pid) * 64 + lane] = fmaxf(hmax, 0.0f);
  }
}

extern "C" void kernel_launch(void* const* d_in, const int* in_sizes, int n_in,
                              void* d_out, int out_size, void* d_ws, size_t ws_size,
                              hipStream_t stream) {
  const float* x  = (const float*)d_in[0];
  // d_in[1] = batch (implicit: i / N) — unused
  const float* W  = (const float*)d_in[2];
  const float* b  = (const float*)d_in[3];
  float* out = (float*)d_out;

  dim3 grid(8 * BPB);   // 512 blocks: 8 batches x 64 point-groups
  dim3 block(BLK);
  hipLaunchKernelGGL(edgeconv_kernel, grid, block, 0, stream, x, W, b, out);
}